// Round 7
// baseline (243.719 us; speedup 1.0000x reference)
//
#include <hip/hip_runtime.h>
#include <math.h>

#define KN   20000
#define IN_  50000
#define DD   128
#define NN   70000
#define E1N  320000
#define E2N  640000
#define ETOT 1600000   // E1N + 2*E2N

// gemm tiles: 64 rows/block (dir 313, ke 1094, ek 1094)
#define GB0  313
#define GB1  1094
#define GTILES 2501

// embedded insert: 3 edges/thread, 768 edges/block -> blocks 0..2083 cover all
#define EPB  768

// padded buckets: 64 slots per segment, start = seg*64. Segment index space:
// dir [0,20000), ke [20000,40000), ek [40000,90000)
#define CAP   64
#define LCAP  6
#define NSEG  90000

typedef _Float16 f16x8 __attribute__((ext_vector_type(8)));
typedef float floatx4 __attribute__((ext_vector_type(4)));

__device__ __forceinline__ unsigned f2bf(float x) {
  unsigned u = __float_as_uint(x);
  return (u + 0x7FFFu + ((u >> 16) & 1u)) >> 16;   // RNE
}
__device__ __forceinline__ unsigned packbf(float a, float b) {
  return f2bf(a) | (f2bf(b) << 16);
}
__device__ __forceinline__ float bf_lo(unsigned u) { return __uint_as_float(u << 16); }
__device__ __forceinline__ float bf_hi(unsigned u) { return __uint_as_float(u & 0xFFFF0000u); }

__device__ __forceinline__ float ftanh(float x) {
  x = fminf(15.f, fmaxf(-15.f, x));
  float t = __expf(2.f * x);
  return (t - 1.f) / (t + 1.f);
}

// Convert one fp32 DxD weight matrix (L2-hot, 64KB) into MFMA-fragment-ordered
// fp16 in LDS. Fragment fi=(t*4+chunk)*64+lane holds
// W[chunk*32+(lane>>4)*8+j][t*16+(lane&15)], j=0..7.
__device__ __forceinline__ void stage_w(const float* __restrict__ W,
                                        short* __restrict__ sW, int tid) {
#pragma unroll
  for (int it = 0; it < 8; ++it) {
    int fi = it * 256 + tid;
    int l = fi & 63, chunk = (fi >> 6) & 3, t = fi >> 8;
    int col = t * 16 + (l & 15);
    int kbase = chunk * 32 + (l >> 4) * 8;
    f16x8 hv;
#pragma unroll
    for (int j = 0; j < 8; ++j) hv[j] = (_Float16)W[(kbase + j) * 128 + col];
    ((f16x8*)sW)[fi] = hv;
  }
}

// Homogeneous gemm grid with EMBEDDED edge insert (issue-early / commit-late):
// after the weight-staging barrier each thread decodes 3 edges and issues 3
// independent atomicAdds; the results are first used AFTER the full MFMA +
// epilogue phase, so the atomic latency hides under ~all of the block's gemm
// work within the same wave. Bucket stores commit at block end.
__global__ __launch_bounds__(256, 4) void gemm3i(
    const float* __restrict__ kn, const float* __restrict__ ex,
    const float* __restrict__ W_dir, const float* __restrict__ W_ke, const float* __restrict__ W_ek,
    const float* __restrict__ a_dir, const float* __restrict__ a_ke, const float* __restrict__ a_ek,
    unsigned* __restrict__ zb_dir, unsigned* __restrict__ zb_ke, unsigned* __restrict__ zb_ek,
    float* __restrict__ sds, float* __restrict__ sdd,
    float* __restrict__ sks, float* __restrict__ skd,
    float* __restrict__ ses, float* __restrict__ sed,
    const int* __restrict__ dsrc, const int* __restrict__ ddst,
    const int* __restrict__ kesrc, const int* __restrict__ kedst,
    const int* __restrict__ eksrc, const int* __restrict__ ekdst,
    int* __restrict__ cur, int* __restrict__ epp)
{
  __shared__ short sW[16384];   // 32 KB fp16 fragments
  const int bid = blockIdx.x;
  const int tid = threadIdx.x;

  // ---- select gemm config ----
  const float *h1, *h2, *avec, *W;
  unsigned* zb;
  float *ssrc, *sdst;
  int split, rows, tile;
  if (bid < GB0) {
    tile = bid; rows = KN; split = KN; h1 = kn; h2 = kn;
    W = W_dir; avec = a_dir; zb = zb_dir; ssrc = sds; sdst = sdd;
  } else if (bid < GB0 + GB1) {
    tile = bid - GB0; rows = NN; split = IN_; h1 = ex; h2 = kn;
    W = W_ke; avec = a_ke; zb = zb_ke; ssrc = sks; sdst = skd;
  } else {
    tile = bid - GB0 - GB1; rows = NN; split = IN_; h1 = ex; h2 = kn;
    W = W_ek; avec = a_ek; zb = zb_ek; ssrc = ses; sdst = sed;
  }

  stage_w(W, sW, tid);
  __syncthreads();

  // ---- insert ISSUE phase: decode 3 edges, fire 3 independent atomics ----
  int ci[3], sv[3], pp[3];
  {
    const int ebase = bid * EPB + tid;
#pragma unroll
    for (int k = 0; k < 3; ++k) {
      int e = ebase + k * 256;
      int c = -1, s = 0;
      if (e < E1N) {
        s = dsrc[e];
        c = ddst[e];
      } else if (e < E1N + E2N) {
        int i = e - E1N;
        s = kesrc[i];
        int d = kedst[i];
        c = (d >= IN_) ? (20000 + d - IN_) : -1;
      } else if (e < ETOT) {
        int i = e - E1N - E2N;
        s = eksrc[i];
        int d = ekdst[i];
        c = (d < IN_) ? (40000 + d) : -1;
      }
      ci[k] = c; sv[k] = s;
      pp[k] = (c >= 0) ? atomicAdd(&cur[c], 1) : 0;   // result unused until commit
    }
  }

  // ---- gemm phase ----
  const int lane = tid & 63;
  const int wv = tid >> 6;
  const int q = lane >> 4;
  const int m = lane & 15;
  const int rr = tile * 64 + wv * 16 + m;
  const int rc = (rr < rows) ? rr : (rows - 1);
  const float* hp = (rc < split) ? (h1 + (size_t)rc * 128)
                                 : (h2 + (size_t)(rc - split) * 128);

  floatx4 acc[8];
#pragma unroll
  for (int t = 0; t < 8; ++t) { acc[t][0]=0.f; acc[t][1]=0.f; acc[t][2]=0.f; acc[t][3]=0.f; }

#pragma unroll
  for (int chunk = 0; chunk < 4; ++chunk) {
    float4 v0 = *(const float4*)(hp + chunk * 32 + q * 8);
    float4 v1 = *(const float4*)(hp + chunk * 32 + q * 8 + 4);
    float vs[8] = {v0.x, v0.y, v0.z, v0.w, v1.x, v1.y, v1.z, v1.w};
    f16x8 ahi, alo;
#pragma unroll
    for (int j = 0; j < 8; ++j) {
      _Float16 h = (_Float16)vs[j];
      ahi[j] = h;
      alo[j] = (_Float16)(vs[j] - (float)h);
    }
#pragma unroll
    for (int t = 0; t < 8; ++t) {
      f16x8 bh = ((const f16x8*)sW)[(t * 4 + chunk) * 64 + lane];
      acc[t] = __builtin_amdgcn_mfma_f32_16x16x32_f16(bh, ahi, acc[t], 0, 0, 0);
      acc[t] = __builtin_amdgcn_mfma_f32_16x16x32_f16(bh, alo, acc[t], 0, 0, 0);
    }
  }

  if (rr < rows) {
    unsigned* zrow = zb + (size_t)rr * 64;
#pragma unroll
    for (int t = 0; t < 8; ++t) {
      uint2 pk;
      pk.x = packbf(acc[t][0], acc[t][1]);
      pk.y = packbf(acc[t][2], acc[t][3]);
      *(uint2*)(zrow + t * 8 + q * 2) = pk;
    }
  }
  float d1 = 0.f, d2 = 0.f;
#pragma unroll
  for (int t = 0; t < 8; ++t) {
    float4 wa = *(const float4*)(avec + t * 16 + q * 4);
    float4 wb = *(const float4*)(avec + 128 + t * 16 + q * 4);
    d1 += acc[t][0] * wa.x + acc[t][1] * wa.y + acc[t][2] * wa.z + acc[t][3] * wa.w;
    d2 += acc[t][0] * wb.x + acc[t][1] * wb.y + acc[t][2] * wb.z + acc[t][3] * wb.w;
  }
  d1 += __shfl_xor(d1, 16, 64); d1 += __shfl_xor(d1, 32, 64);
  d2 += __shfl_xor(d2, 16, 64); d2 += __shfl_xor(d2, 32, 64);
  if (q == 0 && rr < rows) { ssrc[rr] = d1; sdst[rr] = d2; }

  // ---- insert COMMIT phase: first use of atomic results ----
#pragma unroll
  for (int k = 0; k < 3; ++k) {
    if (ci[k] >= 0 && pp[k] < CAP) epp[(ci[k] << LCAP) + pp[k]] = sv[k];
  }
}

// TWO segments per wave (one per 32-lane half). Padded buckets: start=seg*64,
// only cnt needs loading (one int2 per wave covers both segments). Edge slot
// holds src only; logit = ssrc[src] (random 4B, L2/L3-resident) + sd
// (per-segment constant). cnt<=32 staged; rare tail loop to CAP.
__global__ __launch_bounds__(256) void gat_gather(
    const int* __restrict__ cur_dir, const int* __restrict__ epp_dir,
    const float* __restrict__ sds, const float* __restrict__ sdd,
    const unsigned* __restrict__ zb_dir, float* __restrict__ A,
    const int* __restrict__ cur_ke, const int* __restrict__ epp_ke,
    const float* __restrict__ sks, const float* __restrict__ skd,
    const unsigned* __restrict__ zb_ke, float* __restrict__ Bm,
    const int* __restrict__ cur_ek, const int* __restrict__ epp_ek,
    const float* __restrict__ ses, const float* __restrict__ sed,
    const unsigned* __restrict__ zb_ek, float* __restrict__ Cout)
{
  int gw = (blockIdx.x * 256 + threadIdx.x) >> 6;   // global wave id
  int lane = threadIdx.x & 63;
  int h = lane >> 5;          // half: 0 or 1
  int ln31 = lane & 31;
  int gh = (lane >> 4) & 1;   // group within half
  int gl = lane & 15;

  const int *cur, *ep;
  const float *ss, *sD;
  const unsigned* zb;
  float* out;
  int s0, nodeoff;
  if (gw < 10000)      { s0 = 2 * gw;           cur = cur_dir; ep = epp_dir; ss = sds; sD = sdd; zb = zb_dir; out = A;    nodeoff = 0; }
  else if (gw < 20000) { s0 = 2 * (gw - 10000); cur = cur_ke;  ep = epp_ke;  ss = sks; sD = skd; zb = zb_ke;  out = Bm;   nodeoff = IN_; }
  else                 { s0 = 2 * (gw - 20000); cur = cur_ek;  ep = epp_ek;  ss = ses; sD = sed; zb = zb_ek;  out = Cout; nodeoff = 0; }

  // one 8B load fetches cnt for BOTH segments
  int2 cc = *(const int2*)(cur + s0);
  int cnt = h ? cc.y : cc.x;
  cnt = (cnt < CAP) ? cnt : CAP;
  int b = (s0 + h) << LCAP;
  float sd = sD[s0 + h + nodeoff];
  int lim = (cnt < 32) ? cnt : 32;

  // Stage: one coalesced 4B/lane load covers both halves' edge lists.
  int   src_l = 0;
  float w_l   = 0.f;
  if (ln31 < lim) {
    int s = ep[b + ln31];
    src_l = s;
    float x = ss[s] + sd;
    x = (x > 0.f) ? x : 0.01f * x;
    w_l = __expf(x);
  }

  // per-half denominator (xor offsets < 32 stay within the half)
  float den = w_l;
  den += __shfl_xor(den, 1, 64);
  den += __shfl_xor(den, 2, 64);
  den += __shfl_xor(den, 4, 64);
  den += __shfl_xor(den, 8, 64);
  den += __shfl_xor(den, 16, 64);

  float av[8];
#pragma unroll
  for (int k = 0; k < 8; ++k) av[k] = 0.f;

  // z loop: 8 edges per half per iteration (2 groups x 4), 16 rows in flight.
  for (int j0 = 0; j0 < lim; j0 += 8) {
    int base = h * 32 + j0 + gh * 4;
    int   s1 = __shfl(src_l, base + 0, 64); float w1 = __shfl(w_l, base + 0, 64);
    int   s2 = __shfl(src_l, base + 1, 64); float w2 = __shfl(w_l, base + 1, 64);
    int   s3 = __shfl(src_l, base + 2, 64); float w3 = __shfl(w_l, base + 2, 64);
    int   s4 = __shfl(src_l, base + 3, 64); float w4 = __shfl(w_l, base + 3, 64);
    uint4 za = *(const uint4*)(zb + (size_t)s1 * 64 + gl * 4);
    uint4 zc = *(const uint4*)(zb + (size_t)s2 * 64 + gl * 4);
    uint4 ze = *(const uint4*)(zb + (size_t)s3 * 64 + gl * 4);
    uint4 zg = *(const uint4*)(zb + (size_t)s4 * 64 + gl * 4);
    av[0] += w1 * bf_lo(za.x); av[1] += w1 * bf_hi(za.x);
    av[2] += w1 * bf_lo(za.y); av[3] += w1 * bf_hi(za.y);
    av[4] += w1 * bf_lo(za.z); av[5] += w1 * bf_hi(za.z);
    av[6] += w1 * bf_lo(za.w); av[7] += w1 * bf_hi(za.w);
    av[0] += w2 * bf_lo(zc.x); av[1] += w2 * bf_hi(zc.x);
    av[2] += w2 * bf_lo(zc.y); av[3] += w2 * bf_hi(zc.y);
    av[4] += w2 * bf_lo(zc.z); av[5] += w2 * bf_hi(zc.z);
    av[6] += w2 * bf_lo(zc.w); av[7] += w2 * bf_hi(zc.w);
    av[0] += w3 * bf_lo(ze.x); av[1] += w3 * bf_hi(ze.x);
    av[2] += w3 * bf_lo(ze.y); av[3] += w3 * bf_hi(ze.y);
    av[4] += w3 * bf_lo(ze.z); av[5] += w3 * bf_hi(ze.z);
    av[6] += w3 * bf_lo(ze.w); av[7] += w3 * bf_hi(ze.w);
    av[0] += w4 * bf_lo(zg.x); av[1] += w4 * bf_hi(zg.x);
    av[2] += w4 * bf_lo(zg.y); av[3] += w4 * bf_hi(zg.y);
    av[4] += w4 * bf_lo(zg.z); av[5] += w4 * bf_hi(zg.z);
    av[6] += w4 * bf_lo(zg.w); av[7] += w4 * bf_hi(zg.w);
  }

  // tail (32 < cnt <= 64): per-half, 2 groups stride-2 over remaining edges
  if (cnt > 32) {
    float dtail = 0.f;
    int e = b + cnt;
    for (int i = b + 32 + gh; i < e; i += 2) {
      int sx = ep[i];
      float x1 = ss[sx] + sd;
      x1 = (x1 > 0.f) ? x1 : 0.01f * x1;
      float w1 = __expf(x1);
      uint4 za = *(const uint4*)(zb + (size_t)sx * 64 + gl * 4);
      dtail += w1;
      av[0] += w1 * bf_lo(za.x); av[1] += w1 * bf_hi(za.x);
      av[2] += w1 * bf_lo(za.y); av[3] += w1 * bf_hi(za.y);
      av[4] += w1 * bf_lo(za.z); av[5] += w1 * bf_hi(za.z);
      av[6] += w1 * bf_lo(za.w); av[7] += w1 * bf_hi(za.w);
    }
    den += dtail + __shfl_xor(dtail, 16, 64);
  }

  // combine the half's two groups; halves stay independent (no xor 32)
#pragma unroll
  for (int k = 0; k < 8; ++k) av[k] += __shfl_xor(av[k], 16, 64);

  if (cnt > 0) {
    float inv = 1.f / den;
#pragma unroll
    for (int k = 0; k < 8; ++k) av[k] *= inv;
  }

  if (gh == 0) {
    int seg = s0 + h;
    float* op = out + (size_t)seg * 128 + gl * 8;
    *(float4*)op       = make_float4(av[0], av[1], av[2], av[3]);
    *(float4*)(op + 4) = make_float4(av[4], av[5], av[6], av[7]);
  }
}

// rel-gemm on Am and Bm rows (fp16 2-term, rW1 converted inline) +
// fast-tanh/w2 scores + softmax + combine.
__global__ __launch_bounds__(256, 2) void relgemm_combine(
    const float* __restrict__ Am, const float* __restrict__ Bm,
    const float* __restrict__ rW1,
    const float* __restrict__ rb1, const float* __restrict__ rw2,
    float* __restrict__ out)
{
  __shared__ short sW[16384];
  const int tid = threadIdx.x;
  stage_w(rW1, sW, tid);
  __syncthreads();

  const int lane = tid & 63;
  const int wv = tid >> 6;
  const int q = lane >> 4;
  const int m = lane & 15;
  const int r = blockIdx.x * 64 + wv * 16 + m;
  const int rc = (r < KN) ? r : (KN - 1);
  const float* hA = Am + (size_t)rc * 128;
  const float* hB = Bm + (size_t)rc * 128;

  floatx4 accA[8], accB[8];
#pragma unroll
  for (int t = 0; t < 8; ++t) {
    accA[t][0]=0.f; accA[t][1]=0.f; accA[t][2]=0.f; accA[t][3]=0.f;
    accB[t][0]=0.f; accB[t][1]=0.f; accB[t][2]=0.f; accB[t][3]=0.f;
  }

#pragma unroll
  for (int chunk = 0; chunk < 4; ++chunk) {
    float4 a0 = *(const float4*)(hA + chunk * 32 + q * 8);
    float4 a1 = *(const float4*)(hA + chunk * 32 + q * 8 + 4);
    float4 b0 = *(const float4*)(hB + chunk * 32 + q * 8);
    float4 b1 = *(const float4*)(hB + chunk * 32 + q * 8 + 4);
    float as[8] = {a0.x, a0.y, a0.z, a0.w, a1.x, a1.y, a1.z, a1.w};
    float bs[8] = {b0.x, b0.y, b0.z, b0.w, b1.x, b1.y, b1.z, b1.w};
    f16x8 ahiA, aloA, ahiB, aloB;
#pragma unroll
    for (int j = 0; j < 8; ++j) {
      _Float16 ha = (_Float16)as[j];
      ahiA[j] = ha; aloA[j] = (_Float16)(as[j] - (float)ha);
      _Float16 hb = (_Float16)bs[j];
      ahiB[j] = hb; aloB[j] = (_Float16)(bs[j] - (float)hb);
    }
#pragma unroll
    for (int t = 0; t < 8; ++t) {
      f16x8 bh = ((const f16x8*)sW)[(t * 4 + chunk) * 64 + lane];
      accA[t] = __builtin_amdgcn_mfma_f32_16x16x32_f16(bh, ahiA, accA[t], 0, 0, 0);
      accA[t] = __builtin_amdgcn_mfma_f32_16x16x32_f16(bh, aloA, accA[t], 0, 0, 0);
      accB[t] = __builtin_amdgcn_mfma_f32_16x16x32_f16(bh, ahiB, accB[t], 0, 0, 0);
      accB[t] = __builtin_amdgcn_mfma_f32_16x16x32_f16(bh, aloB, accB[t], 0, 0, 0);
    }
  }

  float p1 = 0.f, p2 = 0.f;
#pragma unroll
  for (int t = 0; t < 8; ++t) {
    float4 bb = *(const float4*)(rb1 + t * 16 + q * 4);
    float4 ww = *(const float4*)(rw2 + t * 16 + q * 4);
    p1 += ftanh(accA[t][0] + bb.x) * ww.x + ftanh(accA[t][1] + bb.y) * ww.y +
          ftanh(accA[t][2] + bb.z) * ww.z + ftanh(accA[t][3] + bb.w) * ww.w;
    p2 += ftanh(accB[t][0] + bb.x) * ww.x + ftanh(accB[t][1] + bb.y) * ww.y +
          ftanh(accB[t][2] + bb.z) * ww.z + ftanh(accB[t][3] + bb.w) * ww.w;
  }
  p1 += __shfl_xor(p1, 16, 64); p1 += __shfl_xor(p1, 32, 64);
  p2 += __shfl_xor(p2, 16, 64); p2 += __shfl_xor(p2, 32, 64);

  float mx = fmaxf(p1, p2);
  float e1 = __expf(p1 - mx), e2 = __expf(p2 - mx);
  float al = e1 / (e1 + e2), be = e2 / (e1 + e2);

  if (r < KN) {
#pragma unroll
    for (int t = 0; t < 8; ++t) {
      int col = t * 16 + q * 4;
      float4 avv = *(const float4*)(Am + (size_t)r * 128 + col);
      float4 bvv = *(const float4*)(Bm + (size_t)r * 128 + col);
      *(float4*)(out + (size_t)r * 128 + col) =
          make_float4(al * avv.x + be * bvv.x, al * avv.y + be * bvv.y,
                      al * avv.z + be * bvv.z, al * avv.w + be * bvv.w);
    }
  }
}

extern "C" void kernel_launch(void* const* d_in, const int* in_sizes, int n_in,
                              void* d_out, int out_size, void* d_ws, size_t ws_size,
                              hipStream_t stream) {
  const float* kn    = (const float*)d_in[0];
  const float* ex    = (const float*)d_in[1];
  const float* W_dir = (const float*)d_in[2];
  const float* a_dir = (const float*)d_in[3];
  const float* W_ke  = (const float*)d_in[4];
  const float* a_ke  = (const float*)d_in[5];
  const float* W_ek  = (const float*)d_in[6];
  const float* a_ek  = (const float*)d_in[7];
  const float* rW1   = (const float*)d_in[8];
  const float* rb1   = (const float*)d_in[9];
  const float* rw2   = (const float*)d_in[10];
  const int* dsrc    = (const int*)d_in[11];
  const int* ddst    = (const int*)d_in[12];
  const int* kesrc   = (const int*)d_in[13];
  const int* kedst   = (const int*)d_in[14];
  const int* eksrc   = (const int*)d_in[15];
  const int* ekdst   = (const int*)d_in[16];
  float* out = (float*)d_out;

  char* p = (char*)d_ws;
  auto alloc = [&](size_t bytes) {
    char* r = p;
    p += (bytes + 255) & ~(size_t)255;
    return r;
  };
  unsigned* zb_dir = (unsigned*)alloc((size_t)KN * 64 * 4);
  unsigned* zb_ke  = (unsigned*)alloc((size_t)NN * 64 * 4);
  unsigned* zb_ek  = (unsigned*)alloc((size_t)NN * 64 * 4);
  float* Am    = (float*)alloc((size_t)KN * 128 * 4);
  float* Bmat  = (float*)alloc((size_t)KN * 128 * 4);
  float* sds = (float*)alloc(KN * 4);
  float* sdd = (float*)alloc(KN * 4);
  float* sks = (float*)alloc(NN * 4);
  float* skd = (float*)alloc(NN * 4);
  float* ses = (float*)alloc(NN * 4);
  float* sed = (float*)alloc(NN * 4);
  int* cur = (int*)alloc((size_t)NSEG * 4);              // cursors (memset 0)
  int* epp = (int*)alloc((size_t)NSEG * CAP * 4);        // padded buckets

  hipMemsetAsync(cur, 0, (size_t)NSEG * 4, stream);

  gemm3i<<<GTILES, 256, 0, stream>>>(
      kn, ex, W_dir, W_ke, W_ek, a_dir, a_ke, a_ek,
      zb_dir, zb_ke, zb_ek,
      sds, sdd, sks, skd, ses, sed,
      dsrc, ddst, kesrc, kedst, eksrc, ekdst,
      cur, epp);

  // 45000 waves (2 segments each) = 11250 blocks
  gat_gather<<<11250, 256, 0, stream>>>(
      cur,          epp,              sds, sdd, zb_dir, Am,
      cur + 20000,  epp + 20000 * CAP, sks, skd, zb_ke,  Bmat,
      cur + 40000,  epp + 40000 * CAP, ses, sed, zb_ek,  out + (size_t)KN * 128);

  relgemm_combine<<<313, 256, 0, stream>>>(Am, Bmat, rW1, rb1, rw2, out);
}

// Round 9
// 239.237 us; speedup vs baseline: 1.0187x; 1.0187x over previous
//
#include <hip/hip_runtime.h>
#include <math.h>

#define KN   20000
#define IN_  50000
#define DD   128
#define NN   70000
#define E1N  320000
#define E2N  640000

// gemm tiles: 64 rows/block (dir 313, ke 1094, ek 1094)
#define GB0  313
#define GB1  1094
#define GB2  1094
#define GTILES 2501

// merged grid: groups of 21 blocks = 16 gemm + 5 insert
#define GROUPS 157          // 157*16=2512 >= 2501 gemm; 157*5=785 >= 782 insert
#define MGRID  (GROUPS*21)
#define CNT_CHUNKS 782      // ceil(200000/256) threads, 8 edges each

// padded buckets: 64 slots per segment, start = seg*64 (no CSR prefix pass)
#define CAP   64
#define LCAP  6

typedef _Float16 f16x8 __attribute__((ext_vector_type(8)));
typedef float floatx4 __attribute__((ext_vector_type(4)));

__device__ __forceinline__ unsigned f2bf(float x) {
  unsigned u = __float_as_uint(x);
  return (u + 0x7FFFu + ((u >> 16) & 1u)) >> 16;   // RNE
}
__device__ __forceinline__ unsigned packbf(float a, float b) {
  return f2bf(a) | (f2bf(b) << 16);
}
__device__ __forceinline__ float bf_lo(unsigned u) { return __uint_as_float(u << 16); }
__device__ __forceinline__ float bf_hi(unsigned u) { return __uint_as_float(u & 0xFFFF0000u); }

__device__ __forceinline__ float ftanh(float x) {
  x = fminf(15.f, fmaxf(-15.f, x));
  float t = __expf(2.f * x);
  return (t - 1.f) / (t + 1.f);
}

// Weight conversion only: 4 matrices -> MFMA-fragment-ordered fp16.
// (Precomputing wfr once is cheaper than per-block inline conversion: R6/R7
// showed inline stage_w costs more than the int4 reload it saves.)
__global__ __launch_bounds__(256) void prep(
    const float* __restrict__ W0, const float* __restrict__ W1,
    const float* __restrict__ W2, const float* __restrict__ W3,
    short* __restrict__ wfr)
{
  int b = blockIdx.x;
  int wsel = b >> 3;
  const float* W = (wsel == 0) ? W0 : (wsel == 1) ? W1 : (wsel == 2) ? W2 : W3;
  int fi = (b & 7) * 256 + threadIdx.x;    // 0..2047
  int l = fi & 63, chunk = (fi >> 6) & 3, t = fi >> 8;
  int col = t * 16 + (l & 15);
  int kbase = chunk * 32 + (l >> 4) * 8;
  f16x8 hv;
#pragma unroll
  for (int j = 0; j < 8; ++j) hv[j] = (_Float16)W[(kbase + j) * 128 + col];
  ((f16x8*)(wfr + wsel * 16384))[fi] = hv;
}

// Merged: MFMA gemms (16 of every 21 blocks) + single-pass bucket insert
// (5 of 21, 8 edges/thread -> 8 independent atomics in flight/thread):
// pos = atomicAdd(cursor[seg],1); bucket[seg*64+pos] = src. Separate insert
// BLOCKS (not fused into gemm waves): R7 showed in-wave atomics serialize
// against the gemm's own vmcnt waits; dedicated co-resident waves overlap.
__global__ __launch_bounds__(256, 4) void gemm3_insert(
    const float* __restrict__ kn, const float* __restrict__ ex,
    const short* __restrict__ wfr,
    const float* __restrict__ a_dir, const float* __restrict__ a_ke, const float* __restrict__ a_ek,
    unsigned* __restrict__ zb_dir, unsigned* __restrict__ zb_ke, unsigned* __restrict__ zb_ek,
    float* __restrict__ sds, float* __restrict__ sdd,
    float* __restrict__ sks, float* __restrict__ skd,
    float* __restrict__ ses, float* __restrict__ sed,
    const int* __restrict__ dsrc, const int* __restrict__ ddst,
    const int* __restrict__ kesrc, const int* __restrict__ kedst,
    const int* __restrict__ eksrc, const int* __restrict__ ekdst,
    int* __restrict__ cur_dir, int* __restrict__ cur_ke, int* __restrict__ cur_ek,
    int* __restrict__ epp_dir, int* __restrict__ epp_ke, int* __restrict__ epp_ek)
{
  __shared__ short sW[16384];   // 32 KB fp16 fragments (gemm role only)
  const int g = blockIdx.x / 21;
  const int r = blockIdx.x % 21;
  const int tid = threadIdx.x;

  if (r >= 16) {
    // ---- insert role: 8 edges per thread, 8 independent atomics ----
    int cidx = g * 5 + (r - 16);
    if (cidx >= CNT_CHUNKS) return;
    int t = cidx * 256 + tid;
    if (t >= 200000) return;
    int ds[8], sv[8];
    if (t < 40000) {                        // directed edges
      int e0 = t * 8;
      *(int4*)(ds)     = *(const int4*)(ddst + e0);
      *(int4*)(ds + 4) = *(const int4*)(ddst + e0 + 4);
      *(int4*)(sv)     = *(const int4*)(dsrc + e0);
      *(int4*)(sv + 4) = *(const int4*)(dsrc + e0 + 4);
      int p[8];
#pragma unroll
      for (int k = 0; k < 8; ++k) p[k] = atomicAdd(&cur_dir[ds[k]], 1);
#pragma unroll
      for (int k = 0; k < 8; ++k)
        if (p[k] < CAP) epp_dir[(ds[k] << LCAP) + p[k]] = sv[k];
    } else if (t < 120000) {                // ke edges (valid if dst >= IN_)
      int e0 = (t - 40000) * 8;
      *(int4*)(ds)     = *(const int4*)(kedst + e0);
      *(int4*)(ds + 4) = *(const int4*)(kedst + e0 + 4);
      *(int4*)(sv)     = *(const int4*)(kesrc + e0);
      *(int4*)(sv + 4) = *(const int4*)(kesrc + e0 + 4);
      int p[8];
#pragma unroll
      for (int k = 0; k < 8; ++k)
        p[k] = (ds[k] >= IN_) ? atomicAdd(&cur_ke[ds[k] - IN_], 1) : CAP;
#pragma unroll
      for (int k = 0; k < 8; ++k)
        if (p[k] < CAP) epp_ke[((ds[k] - IN_) << LCAP) + p[k]] = sv[k];
    } else {                                // ek edges (valid if dst < IN_)
      int e0 = (t - 120000) * 8;
      *(int4*)(ds)     = *(const int4*)(ekdst + e0);
      *(int4*)(ds + 4) = *(const int4*)(ekdst + e0 + 4);
      *(int4*)(sv)     = *(const int4*)(eksrc + e0);
      *(int4*)(sv + 4) = *(const int4*)(eksrc + e0 + 4);
      int p[8];
#pragma unroll
      for (int k = 0; k < 8; ++k)
        p[k] = (ds[k] < IN_) ? atomicAdd(&cur_ek[ds[k]], 1) : CAP;
#pragma unroll
      for (int k = 0; k < 8; ++k)
        if (p[k] < CAP) epp_ek[(ds[k] << LCAP) + p[k]] = sv[k];
    }
    return;
  }

  // ---- gemm role ----
  const int bid = g * 16 + r;
  if (bid >= GTILES) return;

  const float *h1, *h2, *avec;
  unsigned* zb;
  float *ssrc, *sdst;
  const short* wf;
  int split, rows, tile;
  if (bid < GB0) {
    tile = bid; rows = KN; split = KN; h1 = kn; h2 = kn;
    wf = wfr; avec = a_dir; zb = zb_dir; ssrc = sds; sdst = sdd;
  } else if (bid < GB0 + GB1) {
    tile = bid - GB0; rows = NN; split = IN_; h1 = ex; h2 = kn;
    wf = wfr + 16384; avec = a_ke; zb = zb_ke; ssrc = sks; sdst = skd;
  } else {
    tile = bid - GB0 - GB1; rows = NN; split = IN_; h1 = ex; h2 = kn;
    wf = wfr + 32768; avec = a_ek; zb = zb_ek; ssrc = ses; sdst = sed;
  }

  {
    const int4* gs = (const int4*)wf;
    int4* ls = (int4*)sW;
#pragma unroll
    for (int it = 0; it < 8; ++it) ls[it * 256 + tid] = gs[it * 256 + tid];
  }
  __syncthreads();

  const int lane = tid & 63;
  const int wv = tid >> 6;
  const int q = lane >> 4;
  const int m = lane & 15;
  const int rr = tile * 64 + wv * 16 + m;
  const int rc = (rr < rows) ? rr : (rows - 1);
  const float* hp = (rc < split) ? (h1 + (size_t)rc * 128)
                                 : (h2 + (size_t)(rc - split) * 128);

  floatx4 acc[8];
#pragma unroll
  for (int t = 0; t < 8; ++t) { acc[t][0]=0.f; acc[t][1]=0.f; acc[t][2]=0.f; acc[t][3]=0.f; }

#pragma unroll
  for (int chunk = 0; chunk < 4; ++chunk) {
    float4 v0 = *(const float4*)(hp + chunk * 32 + q * 8);
    float4 v1 = *(const float4*)(hp + chunk * 32 + q * 8 + 4);
    float vs[8] = {v0.x, v0.y, v0.z, v0.w, v1.x, v1.y, v1.z, v1.w};
    f16x8 ahi, alo;
#pragma unroll
    for (int j = 0; j < 8; ++j) {
      _Float16 h = (_Float16)vs[j];
      ahi[j] = h;
      alo[j] = (_Float16)(vs[j] - (float)h);
    }
#pragma unroll
    for (int t = 0; t < 8; ++t) {
      f16x8 bh = ((const f16x8*)sW)[(t * 4 + chunk) * 64 + lane];
      acc[t] = __builtin_amdgcn_mfma_f32_16x16x32_f16(bh, ahi, acc[t], 0, 0, 0);
      acc[t] = __builtin_amdgcn_mfma_f32_16x16x32_f16(bh, alo, acc[t], 0, 0, 0);
    }
  }

  if (rr < rows) {
    unsigned* zrow = zb + (size_t)rr * 64;
#pragma unroll
    for (int t = 0; t < 8; ++t) {
      uint2 pk;
      pk.x = packbf(acc[t][0], acc[t][1]);
      pk.y = packbf(acc[t][2], acc[t][3]);
      *(uint2*)(zrow + t * 8 + q * 2) = pk;
    }
  }
  float d1 = 0.f, d2 = 0.f;
#pragma unroll
  for (int t = 0; t < 8; ++t) {
    float4 wa = *(const float4*)(avec + t * 16 + q * 4);
    float4 wb = *(const float4*)(avec + 128 + t * 16 + q * 4);
    d1 += acc[t][0] * wa.x + acc[t][1] * wa.y + acc[t][2] * wa.z + acc[t][3] * wa.w;
    d2 += acc[t][0] * wb.x + acc[t][1] * wb.y + acc[t][2] * wb.z + acc[t][3] * wb.w;
  }
  d1 += __shfl_xor(d1, 16, 64); d1 += __shfl_xor(d1, 32, 64);
  d2 += __shfl_xor(d2, 16, 64); d2 += __shfl_xor(d2, 32, 64);
  if (q == 0 && rr < rows) { ssrc[rr] = d1; sdst[rr] = d2; }
}

// TWO segments per wave (one per 32-lane half). Padded buckets: start=seg*64,
// only cnt needs loading (one int2 per wave covers both segments). Edge slot
// holds src only; logit = ssrc[src] (random 4B, L2/L3-resident) + sd
// (per-segment constant). cnt<=32 staged; 8 z-rows in flight per 16-lane
// group per iteration (doubled MLP vs 4). Rare tail loop to CAP.
__global__ __launch_bounds__(256) void gat_gather(
    const int* __restrict__ cur_dir, const int* __restrict__ epp_dir,
    const float* __restrict__ sds, const float* __restrict__ sdd,
    const unsigned* __restrict__ zb_dir, float* __restrict__ A,
    const int* __restrict__ cur_ke, const int* __restrict__ epp_ke,
    const float* __restrict__ sks, const float* __restrict__ skd,
    const unsigned* __restrict__ zb_ke, float* __restrict__ Bm,
    const int* __restrict__ cur_ek, const int* __restrict__ epp_ek,
    const float* __restrict__ ses, const float* __restrict__ sed,
    const unsigned* __restrict__ zb_ek, float* __restrict__ Cout)
{
  int gw = (blockIdx.x * 256 + threadIdx.x) >> 6;   // global wave id
  int lane = threadIdx.x & 63;
  int h = lane >> 5;          // half: 0 or 1
  int ln31 = lane & 31;
  int gh = (lane >> 4) & 1;   // group within half
  int gl = lane & 15;

  const int *cur, *ep;
  const float *ss, *sD;
  const unsigned* zb;
  float* out;
  int s0, nodeoff;
  if (gw < 10000)      { s0 = 2 * gw;           cur = cur_dir; ep = epp_dir; ss = sds; sD = sdd; zb = zb_dir; out = A;    nodeoff = 0; }
  else if (gw < 20000) { s0 = 2 * (gw - 10000); cur = cur_ke;  ep = epp_ke;  ss = sks; sD = skd; zb = zb_ke;  out = Bm;   nodeoff = IN_; }
  else                 { s0 = 2 * (gw - 20000); cur = cur_ek;  ep = epp_ek;  ss = ses; sD = sed; zb = zb_ek;  out = Cout; nodeoff = 0; }

  // one 8B load fetches cnt for BOTH segments
  int2 cc = *(const int2*)(cur + s0);
  int cnt = h ? cc.y : cc.x;
  cnt = (cnt < CAP) ? cnt : CAP;
  int b = (s0 + h) << LCAP;
  float sd = sD[s0 + h + nodeoff];
  int lim = (cnt < 32) ? cnt : 32;

  // Stage: one coalesced 4B/lane load covers both halves' edge lists.
  int   src_l = 0;
  float w_l   = 0.f;
  if (ln31 < lim) {
    int s = ep[b + ln31];
    src_l = s;
    float x = ss[s] + sd;
    x = (x > 0.f) ? x : 0.01f * x;
    w_l = __expf(x);
  }

  // per-half denominator (xor offsets < 32 stay within the half)
  float den = w_l;
  den += __shfl_xor(den, 1, 64);
  den += __shfl_xor(den, 2, 64);
  den += __shfl_xor(den, 4, 64);
  den += __shfl_xor(den, 8, 64);
  den += __shfl_xor(den, 16, 64);

  float av[8];
#pragma unroll
  for (int k = 0; k < 8; ++k) av[k] = 0.f;

  // z loop: 16 edges per half per iteration (2 groups x 8), 8 rows in flight
  // per group. Lanes with idx >= lim carry w=0/src=0 (safe row-0 reads).
  for (int j0 = 0; j0 < lim; j0 += 16) {
    int base = h * 32 + j0 + gh * 8;
    int   ss8[8];
    float ww8[8];
#pragma unroll
    for (int u = 0; u < 8; ++u) {
      ss8[u] = __shfl(src_l, base + u, 64);
      ww8[u] = __shfl(w_l, base + u, 64);
    }
    uint4 zz[8];
#pragma unroll
    for (int u = 0; u < 8; ++u)
      zz[u] = *(const uint4*)(zb + (size_t)ss8[u] * 64 + gl * 4);
#pragma unroll
    for (int u = 0; u < 8; ++u) {
      float w = ww8[u];
      av[0] += w * bf_lo(zz[u].x); av[1] += w * bf_hi(zz[u].x);
      av[2] += w * bf_lo(zz[u].y); av[3] += w * bf_hi(zz[u].y);
      av[4] += w * bf_lo(zz[u].z); av[5] += w * bf_hi(zz[u].z);
      av[6] += w * bf_lo(zz[u].w); av[7] += w * bf_hi(zz[u].w);
    }
  }

  // tail (32 < cnt <= 64): per-half, 2 groups stride-2 over remaining edges
  if (cnt > 32) {
    float dtail = 0.f;
    int e = b + cnt;
    for (int i = b + 32 + gh; i < e; i += 2) {
      int sx = ep[i];
      float x1 = ss[sx] + sd;
      x1 = (x1 > 0.f) ? x1 : 0.01f * x1;
      float w1 = __expf(x1);
      uint4 za = *(const uint4*)(zb + (size_t)sx * 64 + gl * 4);
      dtail += w1;
      av[0] += w1 * bf_lo(za.x); av[1] += w1 * bf_hi(za.x);
      av[2] += w1 * bf_lo(za.y); av[3] += w1 * bf_hi(za.y);
      av[4] += w1 * bf_lo(za.z); av[5] += w1 * bf_hi(za.z);
      av[6] += w1 * bf_lo(za.w); av[7] += w1 * bf_hi(za.w);
    }
    den += dtail + __shfl_xor(dtail, 16, 64);
  }

  // combine the half's two groups; halves stay independent (no xor 32)
#pragma unroll
  for (int k = 0; k < 8; ++k) av[k] += __shfl_xor(av[k], 16, 64);

  if (cnt > 0) {
    float inv = 1.f / den;
#pragma unroll
    for (int k = 0; k < 8; ++k) av[k] *= inv;
  }

  if (gh == 0) {
    int seg = s0 + h;
    float* op = out + (size_t)seg * 128 + gl * 8;
    *(float4*)op       = make_float4(av[0], av[1], av[2], av[3]);
    *(float4*)(op + 4) = make_float4(av[4], av[5], av[6], av[7]);
  }
}

// rel-gemm on Am and Bm rows (fp16 2-term) + fast-tanh/w2 scores + softmax + combine.
__global__ __launch_bounds__(256, 2) void relgemm_combine(
    const float* __restrict__ Am, const float* __restrict__ Bm,
    const short* __restrict__ wfr_rel,
    const float* __restrict__ rb1, const float* __restrict__ rw2,
    float* __restrict__ out)
{
  __shared__ short sW[16384];
  const int tid = threadIdx.x;
  {
    const int4* gs = (const int4*)wfr_rel;
    int4* ls = (int4*)sW;
#pragma unroll
    for (int it = 0; it < 8; ++it) ls[it * 256 + tid] = gs[it * 256 + tid];
  }
  __syncthreads();

  const int lane = tid & 63;
  const int wv = tid >> 6;
  const int q = lane >> 4;
  const int m = lane & 15;
  const int r = blockIdx.x * 64 + wv * 16 + m;
  const int rc = (r < KN) ? r : (KN - 1);
  const float* hA = Am + (size_t)rc * 128;
  const float* hB = Bm + (size_t)rc * 128;

  floatx4 accA[8], accB[8];
#pragma unroll
  for (int t = 0; t < 8; ++t) {
    accA[t][0]=0.f; accA[t][1]=0.f; accA[t][2]=0.f; accA[t][3]=0.f;
    accB[t][0]=0.f; accB[t][1]=0.f; accB[t][2]=0.f; accB[t][3]=0.f;
  }

#pragma unroll
  for (int chunk = 0; chunk < 4; ++chunk) {
    float4 a0 = *(const float4*)(hA + chunk * 32 + q * 8);
    float4 a1 = *(const float4*)(hA + chunk * 32 + q * 8 + 4);
    float4 b0 = *(const float4*)(hB + chunk * 32 + q * 8);
    float4 b1 = *(const float4*)(hB + chunk * 32 + q * 8 + 4);
    float as[8] = {a0.x, a0.y, a0.z, a0.w, a1.x, a1.y, a1.z, a1.w};
    float bs[8] = {b0.x, b0.y, b0.z, b0.w, b1.x, b1.y, b1.z, b1.w};
    f16x8 ahiA, aloA, ahiB, aloB;
#pragma unroll
    for (int j = 0; j < 8; ++j) {
      _Float16 ha = (_Float16)as[j];
      ahiA[j] = ha; aloA[j] = (_Float16)(as[j] - (float)ha);
      _Float16 hb = (_Float16)bs[j];
      ahiB[j] = hb; aloB[j] = (_Float16)(bs[j] - (float)hb);
    }
#pragma unroll
    for (int t = 0; t < 8; ++t) {
      f16x8 bh = ((const f16x8*)sW)[(t * 4 + chunk) * 64 + lane];
      accA[t] = __builtin_amdgcn_mfma_f32_16x16x32_f16(bh, ahiA, accA[t], 0, 0, 0);
      accA[t] = __builtin_amdgcn_mfma_f32_16x16x32_f16(bh, aloA, accA[t], 0, 0, 0);
      accB[t] = __builtin_amdgcn_mfma_f32_16x16x32_f16(bh, ahiB, accB[t], 0, 0, 0);
      accB[t] = __builtin_amdgcn_mfma_f32_16x16x32_f16(bh, aloB, accB[t], 0, 0, 0);
    }
  }

  float p1 = 0.f, p2 = 0.f;
#pragma unroll
  for (int t = 0; t < 8; ++t) {
    float4 bb = *(const float4*)(rb1 + t * 16 + q * 4);
    float4 ww = *(const float4*)(rw2 + t * 16 + q * 4);
    p1 += ftanh(accA[t][0] + bb.x) * ww.x + ftanh(accA[t][1] + bb.y) * ww.y +
          ftanh(accA[t][2] + bb.z) * ww.z + ftanh(accA[t][3] + bb.w) * ww.w;
    p2 += ftanh(accB[t][0] + bb.x) * ww.x + ftanh(accB[t][1] + bb.y) * ww.y +
          ftanh(accB[t][2] + bb.z) * ww.z + ftanh(accB[t][3] + bb.w) * ww.w;
  }
  p1 += __shfl_xor(p1, 16, 64); p1 += __shfl_xor(p1, 32, 64);
  p2 += __shfl_xor(p2, 16, 64); p2 += __shfl_xor(p2, 32, 64);

  float mx = fmaxf(p1, p2);
  float e1 = __expf(p1 - mx), e2 = __expf(p2 - mx);
  float al = e1 / (e1 + e2), be = e2 / (e1 + e2);

  if (r < KN) {
#pragma unroll
    for (int t = 0; t < 8; ++t) {
      int col = t * 16 + q * 4;
      float4 avv = *(const float4*)(Am + (size_t)r * 128 + col);
      float4 bvv = *(const float4*)(Bm + (size_t)r * 128 + col);
      *(float4*)(out + (size_t)r * 128 + col) =
          make_float4(al * avv.x + be * bvv.x, al * avv.y + be * bvv.y,
                      al * avv.z + be * bvv.z, al * avv.w + be * bvv.w);
    }
  }
}

extern "C" void kernel_launch(void* const* d_in, const int* in_sizes, int n_in,
                              void* d_out, int out_size, void* d_ws, size_t ws_size,
                              hipStream_t stream) {
  const float* kn    = (const float*)d_in[0];
  const float* ex    = (const float*)d_in[1];
  const float* W_dir = (const float*)d_in[2];
  const float* a_dir = (const float*)d_in[3];
  const float* W_ke  = (const float*)d_in[4];
  const float* a_ke  = (const float*)d_in[5];
  const float* W_ek  = (const float*)d_in[6];
  const float* a_ek  = (const float*)d_in[7];
  const float* rW1   = (const float*)d_in[8];
  const float* rb1   = (const float*)d_in[9];
  const float* rw2   = (const float*)d_in[10];
  const int* dsrc    = (const int*)d_in[11];
  const int* ddst    = (const int*)d_in[12];
  const int* kesrc   = (const int*)d_in[13];
  const int* kedst   = (const int*)d_in[14];
  const int* eksrc   = (const int*)d_in[15];
  const int* ekdst   = (const int*)d_in[16];
  float* out = (float*)d_out;

  char* p = (char*)d_ws;
  auto alloc = [&](size_t bytes) {
    char* r = p;
    p += (bytes + 255) & ~(size_t)255;
    return r;
  };
  unsigned* zb_dir = (unsigned*)alloc((size_t)KN * 64 * 4);
  unsigned* zb_ke  = (unsigned*)alloc((size_t)NN * 64 * 4);
  unsigned* zb_ek  = (unsigned*)alloc((size_t)NN * 64 * 4);
  float* Am    = (float*)alloc((size_t)KN * 128 * 4);
  float* Bmat  = (float*)alloc((size_t)KN * 128 * 4);
  short* wfr   = (short*)alloc((size_t)4 * 16384 * 2);
  float* sds = (float*)alloc(KN * 4);
  float* sdd = (float*)alloc(KN * 4);
  float* sks = (float*)alloc(NN * 4);
  float* skd = (float*)alloc(NN * 4);
  float* ses = (float*)alloc(NN * 4);
  float* sed = (float*)alloc(NN * 4);
  int* cur = (int*)alloc((size_t)(KN + KN + IN_) * 4);   // cursors (memset 0)
  int* cur_dir = cur;
  int* cur_ke  = cur + KN;
  int* cur_ek  = cur + 2 * KN;
  int* epp_dir = (int*)alloc((size_t)KN * CAP * 4);
  int* epp_ke  = (int*)alloc((size_t)KN * CAP * 4);
  int* epp_ek  = (int*)alloc((size_t)IN_ * CAP * 4);

  hipMemsetAsync(cur, 0, (size_t)(KN + KN + IN_) * 4, stream);

  prep<<<32, 256, 0, stream>>>(W_dir, W_ke, W_ek, rW1, wfr);

  gemm3_insert<<<MGRID, 256, 0, stream>>>(
      kn, ex, wfr, a_dir, a_ke, a_ek,
      zb_dir, zb_ke, zb_ek,
      sds, sdd, sks, skd, ses, sed,
      dsrc, ddst, kesrc, kedst, eksrc, ekdst,
      cur_dir, cur_ke, cur_ek,
      epp_dir, epp_ke, epp_ek);

  // 45000 waves (2 segments each) = 11250 blocks
  gat_gather<<<11250, 256, 0, stream>>>(
      cur_dir, epp_dir, sds, sdd, zb_dir, Am,
      cur_ke,  epp_ke,  sks, skd, zb_ke,  Bmat,
      cur_ek,  epp_ek,  ses, sed, zb_ek,  out + (size_t)KN * 128);

  relgemm_combine<<<313, 256, 0, stream>>>(Am, Bmat, wfr + 3 * 16384, rb1, rw2, out);
}

// Round 10
// 226.997 us; speedup vs baseline: 1.0737x; 1.0539x over previous
//
#include <hip/hip_runtime.h>
#include <math.h>

#define KN   20000
#define IN_  50000
#define DD   128
#define NN   70000
#define E1N  320000
#define E2N  640000

// gemm tiles: 64 rows/block (dir 313, ke 1094, ek 1094)
#define GB0  313
#define GB1  1094
#define GB2  1094
#define GTILES 2501

// merged grid: groups of 13 blocks = 8 gemm + 5 insert  (R5-proven ratio)
#define GROUPS 313          // 313*8=2504 >= 2501 gemm; 313*5=1565 >= 1563 insert
#define MGRID  (GROUPS*13)
#define CNT_CHUNKS 1563     // ceil(400000/256) threads, 4 edges each

// padded buckets: 64 slots per segment, start = seg*64 (no CSR prefix pass)
#define CAP   64
#define LCAP  6

// cursor padding: ONE cursor per 64B cache line (16 ints). Removes same-line
// serialization between atomics to DIFFERENT dst counters (LLC atomic unit
// locks per line; 16 packed cursors/line made 16 dsts serialize as one).
#define CPAD  16

typedef _Float16 f16x8 __attribute__((ext_vector_type(8)));
typedef float floatx4 __attribute__((ext_vector_type(4)));

__device__ __forceinline__ unsigned f2bf(float x) {
  unsigned u = __float_as_uint(x);
  return (u + 0x7FFFu + ((u >> 16) & 1u)) >> 16;   // RNE
}
__device__ __forceinline__ unsigned packbf(float a, float b) {
  return f2bf(a) | (f2bf(b) << 16);
}
__device__ __forceinline__ float bf_lo(unsigned u) { return __uint_as_float(u << 16); }
__device__ __forceinline__ float bf_hi(unsigned u) { return __uint_as_float(u & 0xFFFF0000u); }

__device__ __forceinline__ float ftanh(float x) {
  x = fminf(15.f, fmaxf(-15.f, x));
  float t = __expf(2.f * x);
  return (t - 1.f) / (t + 1.f);
}

// Weight conversion only: 4 matrices -> MFMA-fragment-ordered fp16.
__global__ __launch_bounds__(256) void prep(
    const float* __restrict__ W0, const float* __restrict__ W1,
    const float* __restrict__ W2, const float* __restrict__ W3,
    short* __restrict__ wfr)
{
  int b = blockIdx.x;
  int wsel = b >> 3;
  const float* W = (wsel == 0) ? W0 : (wsel == 1) ? W1 : (wsel == 2) ? W2 : W3;
  int fi = (b & 7) * 256 + threadIdx.x;    // 0..2047
  int l = fi & 63, chunk = (fi >> 6) & 3, t = fi >> 8;
  int col = t * 16 + (l & 15);
  int kbase = chunk * 32 + (l >> 4) * 8;
  f16x8 hv;
#pragma unroll
  for (int j = 0; j < 8; ++j) hv[j] = (_Float16)W[(kbase + j) * 128 + col];
  ((f16x8*)(wfr + wsel * 16384))[fi] = hv;
}

// Merged: MFMA gemms (8 of every 13 blocks) + single-pass bucket insert
// (5 of 13, 4 edges/thread — R5-proven config; R9 showed 8/thread regresses).
// pos = atomicAdd(cursor[seg*CPAD],1); bucket[seg*64+pos] = src.
__global__ __launch_bounds__(256, 4) void gemm3_insert(
    const float* __restrict__ kn, const float* __restrict__ ex,
    const short* __restrict__ wfr,
    const float* __restrict__ a_dir, const float* __restrict__ a_ke, const float* __restrict__ a_ek,
    unsigned* __restrict__ zb_dir, unsigned* __restrict__ zb_ke, unsigned* __restrict__ zb_ek,
    float* __restrict__ sds, float* __restrict__ sdd,
    float* __restrict__ sks, float* __restrict__ skd,
    float* __restrict__ ses, float* __restrict__ sed,
    const int* __restrict__ dsrc, const int* __restrict__ ddst,
    const int* __restrict__ kesrc, const int* __restrict__ kedst,
    const int* __restrict__ eksrc, const int* __restrict__ ekdst,
    int* __restrict__ cur_dir, int* __restrict__ cur_ke, int* __restrict__ cur_ek,
    int* __restrict__ epp_dir, int* __restrict__ epp_ke, int* __restrict__ epp_ek)
{
  __shared__ short sW[16384];   // 32 KB fp16 fragments (gemm role only)
  const int g = blockIdx.x / 13;
  const int r = blockIdx.x % 13;
  const int tid = threadIdx.x;

  if (r >= 8) {
    // ---- insert role: 4 edges per thread, independent atomics ----
    int cidx = g * 5 + (r - 8);
    if (cidx >= CNT_CHUNKS) return;
    int t = cidx * 256 + tid;
    if (t < 80000) {                       // directed edges
      int e0 = t * 4;
      int4 s4 = *(const int4*)(dsrc + e0);
      int4 d4 = *(const int4*)(ddst + e0);
      int p;
      p = atomicAdd(&cur_dir[d4.x * CPAD], 1); if (p < CAP) epp_dir[(d4.x << LCAP) + p] = s4.x;
      p = atomicAdd(&cur_dir[d4.y * CPAD], 1); if (p < CAP) epp_dir[(d4.y << LCAP) + p] = s4.y;
      p = atomicAdd(&cur_dir[d4.z * CPAD], 1); if (p < CAP) epp_dir[(d4.z << LCAP) + p] = s4.z;
      p = atomicAdd(&cur_dir[d4.w * CPAD], 1); if (p < CAP) epp_dir[(d4.w << LCAP) + p] = s4.w;
    } else if (t < 240000) {               // ke edges (valid if dst >= IN_)
      int e0 = (t - 80000) * 4;
      int4 s4 = *(const int4*)(kesrc + e0);
      int4 d4 = *(const int4*)(kedst + e0);
      int p;
      if (d4.x >= IN_) { p = atomicAdd(&cur_ke[(d4.x - IN_) * CPAD], 1); if (p < CAP) epp_ke[((d4.x - IN_) << LCAP) + p] = s4.x; }
      if (d4.y >= IN_) { p = atomicAdd(&cur_ke[(d4.y - IN_) * CPAD], 1); if (p < CAP) epp_ke[((d4.y - IN_) << LCAP) + p] = s4.y; }
      if (d4.z >= IN_) { p = atomicAdd(&cur_ke[(d4.z - IN_) * CPAD], 1); if (p < CAP) epp_ke[((d4.z - IN_) << LCAP) + p] = s4.z; }
      if (d4.w >= IN_) { p = atomicAdd(&cur_ke[(d4.w - IN_) * CPAD], 1); if (p < CAP) epp_ke[((d4.w - IN_) << LCAP) + p] = s4.w; }
    } else if (t < 400000) {               // ek edges (valid if dst < IN_)
      int e0 = (t - 240000) * 4;
      int4 s4 = *(const int4*)(eksrc + e0);
      int4 d4 = *(const int4*)(ekdst + e0);
      int p;
      if (d4.x < IN_) { p = atomicAdd(&cur_ek[d4.x * CPAD], 1); if (p < CAP) epp_ek[(d4.x << LCAP) + p] = s4.x; }
      if (d4.y < IN_) { p = atomicAdd(&cur_ek[d4.y * CPAD], 1); if (p < CAP) epp_ek[(d4.y << LCAP) + p] = s4.y; }
      if (d4.z < IN_) { p = atomicAdd(&cur_ek[d4.z * CPAD], 1); if (p < CAP) epp_ek[(d4.z << LCAP) + p] = s4.z; }
      if (d4.w < IN_) { p = atomicAdd(&cur_ek[d4.w * CPAD], 1); if (p < CAP) epp_ek[(d4.w << LCAP) + p] = s4.w; }
    }
    return;
  }

  // ---- gemm role ----
  const int bid = g * 8 + r;
  if (bid >= GTILES) return;

  const float *h1, *h2, *avec;
  unsigned* zb;
  float *ssrc, *sdst;
  const short* wf;
  int split, rows, tile;
  if (bid < GB0) {
    tile = bid; rows = KN; split = KN; h1 = kn; h2 = kn;
    wf = wfr; avec = a_dir; zb = zb_dir; ssrc = sds; sdst = sdd;
  } else if (bid < GB0 + GB1) {
    tile = bid - GB0; rows = NN; split = IN_; h1 = ex; h2 = kn;
    wf = wfr + 16384; avec = a_ke; zb = zb_ke; ssrc = sks; sdst = skd;
  } else {
    tile = bid - GB0 - GB1; rows = NN; split = IN_; h1 = ex; h2 = kn;
    wf = wfr + 32768; avec = a_ek; zb = zb_ek; ssrc = ses; sdst = sed;
  }

  {
    const int4* gs = (const int4*)wf;
    int4* ls = (int4*)sW;
#pragma unroll
    for (int it = 0; it < 8; ++it) ls[it * 256 + tid] = gs[it * 256 + tid];
  }
  __syncthreads();

  const int lane = tid & 63;
  const int wv = tid >> 6;
  const int q = lane >> 4;
  const int m = lane & 15;
  const int rr = tile * 64 + wv * 16 + m;
  const int rc = (rr < rows) ? rr : (rows - 1);
  const float* hp = (rc < split) ? (h1 + (size_t)rc * 128)
                                 : (h2 + (size_t)(rc - split) * 128);

  floatx4 acc[8];
#pragma unroll
  for (int t = 0; t < 8; ++t) { acc[t][0]=0.f; acc[t][1]=0.f; acc[t][2]=0.f; acc[t][3]=0.f; }

#pragma unroll
  for (int chunk = 0; chunk < 4; ++chunk) {
    float4 v0 = *(const float4*)(hp + chunk * 32 + q * 8);
    float4 v1 = *(const float4*)(hp + chunk * 32 + q * 8 + 4);
    float vs[8] = {v0.x, v0.y, v0.z, v0.w, v1.x, v1.y, v1.z, v1.w};
    f16x8 ahi, alo;
#pragma unroll
    for (int j = 0; j < 8; ++j) {
      _Float16 h = (_Float16)vs[j];
      ahi[j] = h;
      alo[j] = (_Float16)(vs[j] - (float)h);
    }
#pragma unroll
    for (int t = 0; t < 8; ++t) {
      f16x8 bh = ((const f16x8*)sW)[(t * 4 + chunk) * 64 + lane];
      acc[t] = __builtin_amdgcn_mfma_f32_16x16x32_f16(bh, ahi, acc[t], 0, 0, 0);
      acc[t] = __builtin_amdgcn_mfma_f32_16x16x32_f16(bh, alo, acc[t], 0, 0, 0);
    }
  }

  if (rr < rows) {
    unsigned* zrow = zb + (size_t)rr * 64;
#pragma unroll
    for (int t = 0; t < 8; ++t) {
      uint2 pk;
      pk.x = packbf(acc[t][0], acc[t][1]);
      pk.y = packbf(acc[t][2], acc[t][3]);
      *(uint2*)(zrow + t * 8 + q * 2) = pk;
    }
  }
  float d1 = 0.f, d2 = 0.f;
#pragma unroll
  for (int t = 0; t < 8; ++t) {
    float4 wa = *(const float4*)(avec + t * 16 + q * 4);
    float4 wb = *(const float4*)(avec + 128 + t * 16 + q * 4);
    d1 += acc[t][0] * wa.x + acc[t][1] * wa.y + acc[t][2] * wa.z + acc[t][3] * wa.w;
    d2 += acc[t][0] * wb.x + acc[t][1] * wb.y + acc[t][2] * wb.z + acc[t][3] * wb.w;
  }
  d1 += __shfl_xor(d1, 16, 64); d1 += __shfl_xor(d1, 32, 64);
  d2 += __shfl_xor(d2, 16, 64); d2 += __shfl_xor(d2, 32, 64);
  if (q == 0 && rr < rows) { ssrc[rr] = d1; sdst[rr] = d2; }
}

// TWO segments per wave (one per 32-lane half). Padded buckets: start=seg*64.
// cnt loads are per-half broadcast scalars (cursors now line-padded).
// Edge slot holds src only; logit = ssrc[src] + sd. cnt<=32 staged; tail to CAP.
__global__ __launch_bounds__(256) void gat_gather(
    const int* __restrict__ cur_dir, const int* __restrict__ epp_dir,
    const float* __restrict__ sds, const float* __restrict__ sdd,
    const unsigned* __restrict__ zb_dir, float* __restrict__ A,
    const int* __restrict__ cur_ke, const int* __restrict__ epp_ke,
    const float* __restrict__ sks, const float* __restrict__ skd,
    const unsigned* __restrict__ zb_ke, float* __restrict__ Bm,
    const int* __restrict__ cur_ek, const int* __restrict__ epp_ek,
    const float* __restrict__ ses, const float* __restrict__ sed,
    const unsigned* __restrict__ zb_ek, float* __restrict__ Cout)
{
  int gw = (blockIdx.x * 256 + threadIdx.x) >> 6;   // global wave id
  int lane = threadIdx.x & 63;
  int h = lane >> 5;          // half: 0 or 1
  int ln31 = lane & 31;
  int gh = (lane >> 4) & 1;   // group within half
  int gl = lane & 15;

  const int *cur, *ep;
  const float *ss, *sD;
  const unsigned* zb;
  float* out;
  int s0, nodeoff;
  if (gw < 10000)      { s0 = 2 * gw;           cur = cur_dir; ep = epp_dir; ss = sds; sD = sdd; zb = zb_dir; out = A;    nodeoff = 0; }
  else if (gw < 20000) { s0 = 2 * (gw - 10000); cur = cur_ke;  ep = epp_ke;  ss = sks; sD = skd; zb = zb_ke;  out = Bm;   nodeoff = IN_; }
  else                 { s0 = 2 * (gw - 20000); cur = cur_ek;  ep = epp_ek;  ss = ses; sD = sed; zb = zb_ek;  out = Cout; nodeoff = 0; }

  // per-half cnt load (broadcast within the half; two independent loads/wave)
  int cnt = cur[(s0 + h) * CPAD];
  cnt = (cnt < CAP) ? cnt : CAP;
  int b = (s0 + h) << LCAP;
  float sd = sD[s0 + h + nodeoff];
  int lim = (cnt < 32) ? cnt : 32;

  // Stage: one coalesced 4B/lane load covers both halves' edge lists.
  int   src_l = 0;
  float w_l   = 0.f;
  if (ln31 < lim) {
    int s = ep[b + ln31];
    src_l = s;
    float x = ss[s] + sd;
    x = (x > 0.f) ? x : 0.01f * x;
    w_l = __expf(x);
  }

  // per-half denominator (xor offsets < 32 stay within the half)
  float den = w_l;
  den += __shfl_xor(den, 1, 64);
  den += __shfl_xor(den, 2, 64);
  den += __shfl_xor(den, 4, 64);
  den += __shfl_xor(den, 8, 64);
  den += __shfl_xor(den, 16, 64);

  float av[8];
#pragma unroll
  for (int k = 0; k < 8; ++k) av[k] = 0.f;

  // z loop: 8 edges per half per iteration (2 groups x 4), 16 rows in flight.
  for (int j0 = 0; j0 < lim; j0 += 8) {
    int base = h * 32 + j0 + gh * 4;
    int   s1 = __shfl(src_l, base + 0, 64); float w1 = __shfl(w_l, base + 0, 64);
    int   s2 = __shfl(src_l, base + 1, 64); float w2 = __shfl(w_l, base + 1, 64);
    int   s3 = __shfl(src_l, base + 2, 64); float w3 = __shfl(w_l, base + 2, 64);
    int   s4 = __shfl(src_l, base + 3, 64); float w4 = __shfl(w_l, base + 3, 64);
    uint4 za = *(const uint4*)(zb + (size_t)s1 * 64 + gl * 4);
    uint4 zc = *(const uint4*)(zb + (size_t)s2 * 64 + gl * 4);
    uint4 ze = *(const uint4*)(zb + (size_t)s3 * 64 + gl * 4);
    uint4 zg = *(const uint4*)(zb + (size_t)s4 * 64 + gl * 4);
    av[0] += w1 * bf_lo(za.x); av[1] += w1 * bf_hi(za.x);
    av[2] += w1 * bf_lo(za.y); av[3] += w1 * bf_hi(za.y);
    av[4] += w1 * bf_lo(za.z); av[5] += w1 * bf_hi(za.z);
    av[6] += w1 * bf_lo(za.w); av[7] += w1 * bf_hi(za.w);
    av[0] += w2 * bf_lo(zc.x); av[1] += w2 * bf_hi(zc.x);
    av[2] += w2 * bf_lo(zc.y); av[3] += w2 * bf_hi(zc.y);
    av[4] += w2 * bf_lo(zc.z); av[5] += w2 * bf_hi(zc.z);
    av[6] += w2 * bf_lo(zc.w); av[7] += w2 * bf_hi(zc.w);
    av[0] += w3 * bf_lo(ze.x); av[1] += w3 * bf_hi(ze.x);
    av[2] += w3 * bf_lo(ze.y); av[3] += w3 * bf_hi(ze.y);
    av[4] += w3 * bf_lo(ze.z); av[5] += w3 * bf_hi(ze.z);
    av[6] += w3 * bf_lo(ze.w); av[7] += w3 * bf_hi(ze.w);
    av[0] += w4 * bf_lo(zg.x); av[1] += w4 * bf_hi(zg.x);
    av[2] += w4 * bf_lo(zg.y); av[3] += w4 * bf_hi(zg.y);
    av[4] += w4 * bf_lo(zg.z); av[5] += w4 * bf_hi(zg.z);
    av[6] += w4 * bf_lo(zg.w); av[7] += w4 * bf_hi(zg.w);
  }

  // tail (32 < cnt <= 64): per-half, 2 groups stride-2 over remaining edges
  if (cnt > 32) {
    float dtail = 0.f;
    int e = b + cnt;
    for (int i = b + 32 + gh; i < e; i += 2) {
      int sx = ep[i];
      float x1 = ss[sx] + sd;
      x1 = (x1 > 0.f) ? x1 : 0.01f * x1;
      float w1 = __expf(x1);
      uint4 za = *(const uint4*)(zb + (size_t)sx * 64 + gl * 4);
      dtail += w1;
      av[0] += w1 * bf_lo(za.x); av[1] += w1 * bf_hi(za.x);
      av[2] += w1 * bf_lo(za.y); av[3] += w1 * bf_hi(za.y);
      av[4] += w1 * bf_lo(za.z); av[5] += w1 * bf_hi(za.z);
      av[6] += w1 * bf_lo(za.w); av[7] += w1 * bf_hi(za.w);
    }
    den += dtail + __shfl_xor(dtail, 16, 64);
  }

  // combine the half's two groups; halves stay independent (no xor 32)
#pragma unroll
  for (int k = 0; k < 8; ++k) av[k] += __shfl_xor(av[k], 16, 64);

  if (cnt > 0) {
    float inv = 1.f / den;
#pragma unroll
    for (int k = 0; k < 8; ++k) av[k] *= inv;
  }

  if (gh == 0) {
    int seg = s0 + h;
    float* op = out + (size_t)seg * 128 + gl * 8;
    *(float4*)op       = make_float4(av[0], av[1], av[2], av[3]);
    *(float4*)(op + 4) = make_float4(av[4], av[5], av[6], av[7]);
  }
}

// rel-gemm on Am and Bm rows (fp16 2-term) + fast-tanh/w2 scores + softmax + combine.
__global__ __launch_bounds__(256, 2) void relgemm_combine(
    const float* __restrict__ Am, const float* __restrict__ Bm,
    const short* __restrict__ wfr_rel,
    const float* __restrict__ rb1, const float* __restrict__ rw2,
    float* __restrict__ out)
{
  __shared__ short sW[16384];
  const int tid = threadIdx.x;
  {
    const int4* gs = (const int4*)wfr_rel;
    int4* ls = (int4*)sW;
#pragma unroll
    for (int it = 0; it < 8; ++it) ls[it * 256 + tid] = gs[it * 256 + tid];
  }
  __syncthreads();

  const int lane = tid & 63;
  const int wv = tid >> 6;
  const int q = lane >> 4;
  const int m = lane & 15;
  const int r = blockIdx.x * 64 + wv * 16 + m;
  const int rc = (r < KN) ? r : (KN - 1);
  const float* hA = Am + (size_t)rc * 128;
  const float* hB = Bm + (size_t)rc * 128;

  floatx4 accA[8], accB[8];
#pragma unroll
  for (int t = 0; t < 8; ++t) {
    accA[t][0]=0.f; accA[t][1]=0.f; accA[t][2]=0.f; accA[t][3]=0.f;
    accB[t][0]=0.f; accB[t][1]=0.f; accB[t][2]=0.f; accB[t][3]=0.f;
  }

#pragma unroll
  for (int chunk = 0; chunk < 4; ++chunk) {
    float4 a0 = *(const float4*)(hA + chunk * 32 + q * 8);
    float4 a1 = *(const float4*)(hA + chunk * 32 + q * 8 + 4);
    float4 b0 = *(const float4*)(hB + chunk * 32 + q * 8);
    float4 b1 = *(const float4*)(hB + chunk * 32 + q * 8 + 4);
    float as[8] = {a0.x, a0.y, a0.z, a0.w, a1.x, a1.y, a1.z, a1.w};
    float bs[8] = {b0.x, b0.y, b0.z, b0.w, b1.x, b1.y, b1.z, b1.w};
    f16x8 ahiA, aloA, ahiB, aloB;
#pragma unroll
    for (int j = 0; j < 8; ++j) {
      _Float16 ha = (_Float16)as[j];
      ahiA[j] = ha; aloA[j] = (_Float16)(as[j] - (float)ha);
      _Float16 hb = (_Float16)bs[j];
      ahiB[j] = hb; aloB[j] = (_Float16)(bs[j] - (float)hb);
    }
#pragma unroll
    for (int t = 0; t < 8; ++t) {
      f16x8 bh = ((const f16x8*)sW)[(t * 4 + chunk) * 64 + lane];
      accA[t] = __builtin_amdgcn_mfma_f32_16x16x32_f16(bh, ahiA, accA[t], 0, 0, 0);
      accA[t] = __builtin_amdgcn_mfma_f32_16x16x32_f16(bh, aloA, accA[t], 0, 0, 0);
      accB[t] = __builtin_amdgcn_mfma_f32_16x16x32_f16(bh, ahiB, accB[t], 0, 0, 0);
      accB[t] = __builtin_amdgcn_mfma_f32_16x16x32_f16(bh, aloB, accB[t], 0, 0, 0);
    }
  }

  float p1 = 0.f, p2 = 0.f;
#pragma unroll
  for (int t = 0; t < 8; ++t) {
    float4 bb = *(const float4*)(rb1 + t * 16 + q * 4);
    float4 ww = *(const float4*)(rw2 + t * 16 + q * 4);
    p1 += ftanh(accA[t][0] + bb.x) * ww.x + ftanh(accA[t][1] + bb.y) * ww.y +
          ftanh(accA[t][2] + bb.z) * ww.z + ftanh(accA[t][3] + bb.w) * ww.w;
    p2 += ftanh(accB[t][0] + bb.x) * ww.x + ftanh(accB[t][1] + bb.y) * ww.y +
          ftanh(accB[t][2] + bb.z) * ww.z + ftanh(accB[t][3] + bb.w) * ww.w;
  }
  p1 += __shfl_xor(p1, 16, 64); p1 += __shfl_xor(p1, 32, 64);
  p2 += __shfl_xor(p2, 16, 64); p2 += __shfl_xor(p2, 32, 64);

  float mx = fmaxf(p1, p2);
  float e1 = __expf(p1 - mx), e2 = __expf(p2 - mx);
  float al = e1 / (e1 + e2), be = e2 / (e1 + e2);

  if (r < KN) {
#pragma unroll
    for (int t = 0; t < 8; ++t) {
      int col = t * 16 + q * 4;
      float4 avv = *(const float4*)(Am + (size_t)r * 128 + col);
      float4 bvv = *(const float4*)(Bm + (size_t)r * 128 + col);
      *(float4*)(out + (size_t)r * 128 + col) =
          make_float4(al * avv.x + be * bvv.x, al * avv.y + be * bvv.y,
                      al * avv.z + be * bvv.z, al * avv.w + be * bvv.w);
    }
  }
}

extern "C" void kernel_launch(void* const* d_in, const int* in_sizes, int n_in,
                              void* d_out, int out_size, void* d_ws, size_t ws_size,
                              hipStream_t stream) {
  const float* kn    = (const float*)d_in[0];
  const float* ex    = (const float*)d_in[1];
  const float* W_dir = (const float*)d_in[2];
  const float* a_dir = (const float*)d_in[3];
  const float* W_ke  = (const float*)d_in[4];
  const float* a_ke  = (const float*)d_in[5];
  const float* W_ek  = (const float*)d_in[6];
  const float* a_ek  = (const float*)d_in[7];
  const float* rW1   = (const float*)d_in[8];
  const float* rb1   = (const float*)d_in[9];
  const float* rw2   = (const float*)d_in[10];
  const int* dsrc    = (const int*)d_in[11];
  const int* ddst    = (const int*)d_in[12];
  const int* kesrc   = (const int*)d_in[13];
  const int* kedst   = (const int*)d_in[14];
  const int* eksrc   = (const int*)d_in[15];
  const int* ekdst   = (const int*)d_in[16];
  float* out = (float*)d_out;

  char* p = (char*)d_ws;
  auto alloc = [&](size_t bytes) {
    char* r = p;
    p += (bytes + 255) & ~(size_t)255;
    return r;
  };
  unsigned* zb_dir = (unsigned*)alloc((size_t)KN * 64 * 4);
  unsigned* zb_ke  = (unsigned*)alloc((size_t)NN * 64 * 4);
  unsigned* zb_ek  = (unsigned*)alloc((size_t)NN * 64 * 4);
  float* Am    = (float*)alloc((size_t)KN * 128 * 4);
  float* Bmat  = (float*)alloc((size_t)KN * 128 * 4);
  short* wfr   = (short*)alloc((size_t)4 * 16384 * 2);
  float* sds = (float*)alloc(KN * 4);
  float* sdd = (float*)alloc(KN * 4);
  float* sks = (float*)alloc(NN * 4);
  float* skd = (float*)alloc(NN * 4);
  float* ses = (float*)alloc(NN * 4);
  float* sed = (float*)alloc(NN * 4);
  // line-padded cursors: 90000 counters x 64B
  int* cur = (int*)alloc((size_t)(KN + KN + IN_) * CPAD * 4);
  int* cur_dir = cur;
  int* cur_ke  = cur + (size_t)KN * CPAD;
  int* cur_ek  = cur + (size_t)2 * KN * CPAD;
  int* epp_dir = (int*)alloc((size_t)KN * CAP * 4);
  int* epp_ke  = (int*)alloc((size_t)KN * CAP * 4);
  int* epp_ek  = (int*)alloc((size_t)IN_ * CAP * 4);

  hipMemsetAsync(cur, 0, (size_t)(KN + KN + IN_) * CPAD * 4, stream);

  prep<<<32, 256, 0, stream>>>(W_dir, W_ke, W_ek, rW1, wfr);

  gemm3_insert<<<MGRID, 256, 0, stream>>>(
      kn, ex, wfr, a_dir, a_ke, a_ek,
      zb_dir, zb_ke, zb_ek,
      sds, sdd, sks, skd, ses, sed,
      dsrc, ddst, kesrc, kedst, eksrc, ekdst,
      cur_dir, cur_ke, cur_ek,
      epp_dir, epp_ke, epp_ek);

  // 45000 waves (2 segments each) = 11250 blocks
  gat_gather<<<11250, 256, 0, stream>>>(
      cur_dir, epp_dir, sds, sdd, zb_dir, Am,
      cur_ke,  epp_ke,  sks, skd, zb_ke,  Bmat,
      cur_ek,  epp_ek,  ses, sed, zb_ek,  out + (size_t)KN * 128);

  relgemm_combine<<<313, 256, 0, stream>>>(Am, Bmat, wfr + 3 * 16384, rb1, rw2, out);
}